// Round 4
// baseline (4344.461 us; speedup 1.0000x reference)
//
#include <hip/hip_runtime.h>

#define N_NODES 100000
#define N_EDGES 1600000
#define D 128
#define NLAYER 3
#define NSLOT 8
#define NB 1563            // ceil(100000/64) buckets of 64 nodes

typedef __bf16 bf16x8 __attribute__((ext_vector_type(8)));
typedef float f32x4 __attribute__((ext_vector_type(4)));

__device__ inline ushort f2b(float f) {
    union { float f; unsigned u; } v; v.f = f;
    unsigned u = v.u;
    return (ushort)((u + 0x7FFFu + ((u >> 16) & 1u)) >> 16);  // RNE
}
__device__ inline float b2f_lo(unsigned u) {
    union { unsigned u; float f; } v; v.u = u << 16; return v.f;
}
__device__ inline float b2f_hi(unsigned u) {
    union { unsigned u; float f; } v; v.u = u & 0xFFFF0000u; return v.f;
}

// ---------------------------------------------------------------- utility
__global__ void k_zero_i32(int* __restrict__ p, int n) {
    int i = blockIdx.x * blockDim.x + threadIdx.x;
    if (i < n) p[i] = 0;
}

// ---------------------------------------------------------------- bucket build
// LDS-privatized histogram over 1563 buckets (bucket = dst >> 6)
__global__ __launch_bounds__(256)
void k_hist_b(const int* __restrict__ dst, int* __restrict__ bcnt, int e) {
    __shared__ int hs[NB];
    int tid = threadIdx.x;
    for (int i = tid; i < NB; i += 256) hs[i] = 0;
    __syncthreads();
    for (int i = blockIdx.x * 256 + tid; i < e; i += gridDim.x * 256)
        atomicAdd(&hs[dst[i] >> 6], 1);
    __syncthreads();
    for (int i = tid; i < NB; i += 256) {
        int v = hs[i];
        if (v) atomicAdd(&bcnt[i], v);
    }
}

// single-block exclusive scan of NB counts -> boff (+cursor init), boff[NB]=total
__global__ __launch_bounds__(256)
void k_scan_b(const int* __restrict__ bcnt, int* __restrict__ boff,
              int* __restrict__ cur, int total) {
    __shared__ int ts[256];
    int tid = threadIdx.x;
    const int C = (NB + 255) / 256;   // 7
    int s = 0;
    for (int j = 0; j < C; ++j) {
        int i = tid * C + j;
        if (i < NB) s += bcnt[i];
    }
    ts[tid] = s;
    __syncthreads();
    for (int o = 1; o < 256; o <<= 1) {
        int t = (tid >= o) ? ts[tid - o] : 0;
        __syncthreads();
        ts[tid] += t;
        __syncthreads();
    }
    int run = ts[tid] - s;  // exclusive
    for (int j = 0; j < C; ++j) {
        int i = tid * C + j;
        if (i < NB) {
            boff[i] = run; cur[i] = run;
            run += bcnt[i];
        }
    }
    if (tid == 0) boff[NB] = total;
}

// scatter packed edges into bucket-contiguous regions: pack = src*64 | (dst&63)
__global__ __launch_bounds__(256)
void k_bucket(const int* __restrict__ src, const int* __restrict__ dst,
              int* __restrict__ cur, unsigned* __restrict__ bdata, int e) {
    int i = blockIdx.x * 256 + threadIdx.x;
    if (i < e) {
        int d = dst[i];
        int b = d >> 6;
        int p = atomicAdd(&cur[b], 1);
        bdata[p] = ((unsigned)src[i] << 6) | (unsigned)(d & 63);
    }
}

// ---------------------------------------------------------------- aggregation (LDS accumulate)
// accS layout (de-interleaved, bank-conflict-free for wave ds_add):
//   channel c of local row r:  c even -> accS[r*128 + c/2] ; c odd -> accS[r*128 + 64 + c/2]
// Layer 0: h = x fp32, no pre-affine.
__global__ __launch_bounds__(256)
void k_aggL0(const float* __restrict__ x, const int* __restrict__ boff,
             const unsigned* __restrict__ bdata, unsigned* __restrict__ out, int n) {
    __shared__ float accS[64 * 128];   // 32 KB
    int tid = threadIdx.x;
    f32x4* a4 = (f32x4*)accS;
    #pragma unroll
    for (int i = 0; i < 8; ++i) a4[tid + i * 256] = (f32x4){0.f, 0.f, 0.f, 0.f};
    __syncthreads();

    int b = blockIdx.x;
    int e0 = boff[b], ecnt = boff[b + 1] - e0;
    int lane = tid & 63, wv = tid >> 6;
    const float2* x2 = (const float2*)x;

    for (int base = wv * 64; base < ecnt; base += 256) {
        int m = min(64, ecnt - base);
        unsigned myp = (lane < m) ? bdata[e0 + base + lane] : 0;
        for (int j = 0; j < m; ++j) {
            unsigned p = __shfl(myp, j);
            int s = p >> 6, ld = p & 63;
            float2 v = x2[(size_t)s * 64 + lane];   // ch 2*lane, 2*lane+1
            atomicAdd(&accS[ld * 128 + lane], v.x);
            atomicAdd(&accS[ld * 128 + 64 + lane], v.y);
        }
    }
    __syncthreads();

    // write out: out[node] = bf16(x[node] + acc)
    int s16 = tid & 15, r0 = tid >> 4;
    #pragma unroll
    for (int rr = 0; rr < 4; ++rr) {
        int row = rr * 16 + r0;
        int node = b * 64 + row;
        if (node >= n) continue;
        f32x4 lo4 = *(f32x4*)&accS[row * 128 + 4 * s16];        // ch 8s+0,2,4,6
        f32x4 hi4 = *(f32x4*)&accS[row * 128 + 64 + 4 * s16];   // ch 8s+1,3,5,7
        uint4 o;
        unsigned* op = (unsigned*)&o;
        #pragma unroll
        for (int k = 0; k < 4; ++k) {
            float selo = x[(size_t)node * D + 8 * s16 + 2 * k];
            float sehi = x[(size_t)node * D + 8 * s16 + 2 * k + 1];
            op[k] = (unsigned)f2b(lo4[k] + selo) | ((unsigned)f2b(hi4[k] + sehi) << 16);
        }
        *(uint4*)&out[(size_t)node * 64 + 4 * s16] = o;
    }
}

// Layers 1,2: h = raw z2 (bf16); apply fused hval = relu(z*sc + sh) per element.
__global__ __launch_bounds__(256)
void k_aggL(const unsigned* __restrict__ h, const int* __restrict__ boff,
            const unsigned* __restrict__ bdata, const float* __restrict__ sc,
            const float* __restrict__ sh, unsigned* __restrict__ out, int n) {
    __shared__ float accS[64 * 128];
    int tid = threadIdx.x;
    f32x4* a4 = (f32x4*)accS;
    #pragma unroll
    for (int i = 0; i < 8; ++i) a4[tid + i * 256] = (f32x4){0.f, 0.f, 0.f, 0.f};
    __syncthreads();

    int b = blockIdx.x;
    int e0 = boff[b], ecnt = boff[b + 1] - e0;
    int lane = tid & 63, wv = tid >> 6;
    float s0 = sc[2 * lane], s1 = sc[2 * lane + 1];
    float t0 = sh[2 * lane], t1 = sh[2 * lane + 1];

    for (int base = wv * 64; base < ecnt; base += 256) {
        int m = min(64, ecnt - base);
        unsigned myp = (lane < m) ? bdata[e0 + base + lane] : 0;
        for (int j = 0; j < m; ++j) {
            unsigned p = __shfl(myp, j);
            int s = p >> 6, ld = p & 63;
            unsigned u = h[(size_t)s * 64 + lane];
            float lo = b2f_lo(u) * s0 + t0;
            float hi = b2f_hi(u) * s1 + t1;
            lo = lo > 0.f ? lo : 0.f;
            hi = hi > 0.f ? hi : 0.f;
            atomicAdd(&accS[ld * 128 + lane], lo);
            atomicAdd(&accS[ld * 128 + 64 + lane], hi);
        }
    }
    __syncthreads();

    int s16 = tid & 15, r0 = tid >> 4;
    #pragma unroll
    for (int rr = 0; rr < 4; ++rr) {
        int row = rr * 16 + r0;
        int node = b * 64 + row;
        if (node >= n) continue;
        f32x4 lo4 = *(f32x4*)&accS[row * 128 + 4 * s16];
        f32x4 hi4 = *(f32x4*)&accS[row * 128 + 64 + 4 * s16];
        uint4 hu = *(const uint4*)&h[(size_t)node * 64 + 4 * s16];
        const unsigned* hp = (const unsigned*)&hu;
        uint4 o;
        unsigned* op = (unsigned*)&o;
        #pragma unroll
        for (int k = 0; k < 4; ++k) {
            int c = 8 * s16 + 2 * k;
            float selo = b2f_lo(hp[k]) * sc[c] + sh[c];
            float sehi = b2f_hi(hp[k]) * sc[c + 1] + sh[c + 1];
            selo = selo > 0.f ? selo : 0.f;
            sehi = sehi > 0.f ? sehi : 0.f;
            op[k] = (unsigned)f2b(lo4[k] + selo) | ((unsigned)f2b(hi4[k] + sehi) << 16);
        }
        *(uint4*)&out[(size_t)node * 64 + 4 * s16] = o;
    }
}

// ---------------------------------------------------------------- weight prep
__global__ void k_wprep(const float* __restrict__ W, ushort* __restrict__ Wt) {
    int m = blockIdx.y, nn = blockIdx.x, k = threadIdx.x;
    float v = W[(m * D + k) * D + nn];
    Wt[(m * D + nn) * D + k] = f2b(v);
}

// ---------------------------------------------------------------- MFMA GEMM + fused BN stats
__device__ inline bf16x8 load_frag(const ushort* __restrict__ A, int row, int kb, int n,
                                   const float* __restrict__ ps, const float* __restrict__ psh) {
    bf16x8 r;
    if (row >= n) {
        #pragma unroll
        for (int j = 0; j < 8; ++j) r[j] = (__bf16)0.0f;
        return r;
    }
    if (!ps) return *(const bf16x8*)&A[(size_t)row * D + kb];
    unsigned u[4];
    *(uint4*)u = *(const uint4*)&A[(size_t)row * D + kb];
    #pragma unroll
    for (int p = 0; p < 4; ++p) {
        float lo = b2f_lo(u[p]) * ps[kb + 2 * p] + psh[kb + 2 * p];
        float hi = b2f_hi(u[p]) * ps[kb + 2 * p + 1] + psh[kb + 2 * p + 1];
        lo = lo > 0.f ? lo : 0.f;
        hi = hi > 0.f ? hi : 0.f;
        r[2 * p] = (__bf16)lo;
        r[2 * p + 1] = (__bf16)hi;
    }
    return r;
}

__global__ __launch_bounds__(256)
void k_gemm(const ushort* __restrict__ A, const ushort* __restrict__ Wt,
            const float* __restrict__ bias,
            const float* __restrict__ pre_scale, const float* __restrict__ pre_shift,
            ushort* __restrict__ C, float* __restrict__ stats, int n) {
    __shared__ ushort WtS[128 * 136];  // row stride 272 B (17x16B)

    const uint4* wsrc = (const uint4*)Wt;
    #pragma unroll
    for (int j = 0; j < 8; ++j) {
        int i = threadIdx.x + j * 256;   // 0..2047: row = i>>4, seg = i&15
        int r = i >> 4, s16 = i & 15;
        *(uint4*)&WtS[r * 136 + s16 * 8] = wsrc[i];
    }

    int wv   = threadIdx.x >> 6;
    int lane = threadIdx.x & 63;
    int m16  = lane & 15;
    int kq   = lane >> 4;
    int rowbase = blockIdx.x * 128 + wv * 32;

    bf16x8 a0[4], a1[4];
    #pragma unroll
    for (int ks = 0; ks < 4; ++ks) {
        int kb = ks * 32 + kq * 8;
        a0[ks] = load_frag(A, rowbase + m16, kb, n, pre_scale, pre_shift);
        a1[ks] = load_frag(A, rowbase + 16 + m16, kb, n, pre_scale, pre_shift);
    }

    f32x4 acc0[8], acc1[8];
    #pragma unroll
    for (int t = 0; t < 8; ++t) {
        acc0[t] = (f32x4){0.f, 0.f, 0.f, 0.f};
        acc1[t] = (f32x4){0.f, 0.f, 0.f, 0.f};
    }
    __syncthreads();

    #pragma unroll
    for (int ks = 0; ks < 4; ++ks) {
        #pragma unroll
        for (int t = 0; t < 8; ++t) {
            bf16x8 bfr = *(const bf16x8*)&WtS[(t * 16 + m16) * 136 + ks * 32 + kq * 8];
            acc0[t] = __builtin_amdgcn_mfma_f32_16x16x32_bf16(a0[ks], bfr, acc0[t], 0, 0, 0);
            acc1[t] = __builtin_amdgcn_mfma_f32_16x16x32_bf16(a1[ks], bfr, acc1[t], 0, 0, 0);
        }
    }

    int slot = blockIdx.x & (NSLOT - 1);
    #pragma unroll
    for (int t = 0; t < 8; ++t) {
        int col = t * 16 + m16;
        float bz = bias[col];
        float s = 0.f, q = 0.f;
        #pragma unroll
        for (int mt = 0; mt < 2; ++mt) {
            f32x4 v4 = mt ? acc1[t] : acc0[t];
            #pragma unroll
            for (int rr = 0; rr < 4; ++rr) {
                int row = rowbase + mt * 16 + kq * 4 + rr;
                if (row < n) {
                    float v = v4[rr] + bz;
                    C[(size_t)row * D + col] = f2b(v);
                    s += v; q += v * v;
                }
            }
        }
        s += __shfl_xor(s, 16); q += __shfl_xor(q, 16);
        s += __shfl_xor(s, 32); q += __shfl_xor(q, 32);
        if (kq == 0) {
            atomicAdd(&stats[slot * 256 + col], s);
            atomicAdd(&stats[slot * 256 + 128 + col], q);
        }
    }
}

// ---------------------------------------------------------------- BN param fold
__global__ void k_bnparams(const float* __restrict__ stats, const float* __restrict__ gamma,
                           const float* __restrict__ beta, float* __restrict__ scale,
                           float* __restrict__ shift, float inv_n) {
    int c = threadIdx.x;  // 128
    float s = 0.f, q = 0.f;
    for (int sl = 0; sl < NSLOT; ++sl) {
        s += stats[sl * 256 + c];
        q += stats[sl * 256 + 128 + c];
    }
    float mu  = s * inv_n;
    float var = q * inv_n - mu * mu;
    var = var < 0.f ? 0.f : var;
    float rs = rsqrtf(var + 1e-5f);
    float sc = gamma[c] * rs;
    scale[c] = sc;
    shift[c] = beta[c] - mu * sc;
}

// ---------------------------------------------------------------- final BN (fp32 out, no relu)
__global__ __launch_bounds__(256)
void k_final(const unsigned* __restrict__ z, const float* __restrict__ scale,
             const float* __restrict__ shift, float* __restrict__ outf, int total2) {
    int i = blockIdx.x * 256 + threadIdx.x;  // uint2 = 4 bf16
    if (i >= total2) return;
    uint2 u = ((const uint2*)z)[i];
    int c = (i * 4) & (D - 1);
    float4 o;
    o.x = b2f_lo(u.x) * scale[c + 0] + shift[c + 0];
    o.y = b2f_hi(u.x) * scale[c + 1] + shift[c + 1];
    o.z = b2f_lo(u.y) * scale[c + 2] + shift[c + 2];
    o.w = b2f_hi(u.y) * scale[c + 3] + shift[c + 3];
    ((float4*)outf)[i] = o;
}

// ---------------------------------------------------------------- launch
extern "C" void kernel_launch(void* const* d_in, const int* in_sizes, int n_in,
                              void* d_out, int out_size, void* d_ws, size_t ws_size,
                              hipStream_t stream) {
    const float* x   = (const float*)d_in[0];
    const int*   ei  = (const int*)d_in[1];
    const float* W1  = (const float*)d_in[4];
    const float* b1  = (const float*)d_in[5];
    const float* g1  = (const float*)d_in[6];
    const float* be1 = (const float*)d_in[7];
    const float* W2  = (const float*)d_in[8];
    const float* b2  = (const float*)d_in[9];
    const float* g2  = (const float*)d_in[10];
    const float* be2 = (const float*)d_in[11];

    const int* srcI = ei;
    const int* dstI = ei + N_EDGES;

    // workspace layout (~60 MB)
    char* ws = (char*)d_ws;
    unsigned* bufA = (unsigned*)ws; ws += (size_t)N_NODES * 64 * 4 + 65536;
    unsigned* bufB = (unsigned*)ws; ws += (size_t)N_NODES * 64 * 4 + 65536;
    unsigned* bdata = (unsigned*)ws; ws += (size_t)N_EDGES * 4;
    int* bcnt    = (int*)ws;   ws += (NB + 16) * 4;
    int* boff    = (int*)ws;   ws += (NB + 16) * 4;
    int* cur     = (int*)ws;   ws += (NB + 16) * 4;
    ushort* Wt1  = (ushort*)ws; ws += 3 * D * D * 2;
    ushort* Wt2  = (ushort*)ws; ws += 3 * D * D * 2;
    float* stats = (float*)ws; ws += NSLOT * 256 * 4;
    float* scale1 = (float*)ws; ws += 512;
    float* shift1 = (float*)ws; ws += 512;
    float* scale2 = (float*)ws; ws += 512;
    float* shift2 = (float*)ws; ws += 512;

    // ---- weight prep ----
    k_wprep<<<dim3(D, 3), D, 0, stream>>>(W1, Wt1);
    k_wprep<<<dim3(D, 3), D, 0, stream>>>(W2, Wt2);

    // ---- bucket build ----
    k_zero_i32<<<(NB + 255) / 256, 256, 0, stream>>>(bcnt, NB);
    k_hist_b<<<256, 256, 0, stream>>>(dstI, bcnt, N_EDGES);
    k_scan_b<<<1, 256, 0, stream>>>(bcnt, boff, cur, N_EDGES);
    k_bucket<<<(N_EDGES + 255) / 256, 256, 0, stream>>>(srcI, dstI, cur, bdata, N_EDGES);

    const float inv_n = 1.0f / (float)N_NODES;
    int ngemm = (N_NODES + 127) / 128;  // 782

    for (int l = 0; l < NLAYER; ++l) {
        // agg (+ fused BN2/ReLU of previous layer for l>0): -> aggO
        unsigned* aggO = (l == 0) ? bufA : ((l == 1) ? bufB : bufA);
        if (l == 0)
            k_aggL0<<<NB, 256, 0, stream>>>(x, boff, bdata, aggO, N_NODES);
        else {
            const unsigned* hz = (l == 1) ? bufA : bufB;  // previous z2 (raw)
            k_aggL<<<NB, 256, 0, stream>>>(hz, boff, bdata, scale2, shift2, aggO, N_NODES);
        }
        // z1 = aggO @ W1 + b1 -> other buffer, fused col stats
        unsigned* z1 = (aggO == bufA) ? bufB : bufA;
        k_zero_i32<<<NSLOT, 256, 0, stream>>>((int*)stats, NSLOT * 256);
        k_gemm<<<ngemm, 256, 0, stream>>>(
            (const ushort*)aggO, Wt1 + (size_t)l * D * D, b1 + l * D,
            nullptr, nullptr, (ushort*)z1, stats, N_NODES);
        k_bnparams<<<1, D, 0, stream>>>(stats, g1 + l * D, be1 + l * D, scale1, shift1, inv_n);
        // z2 = relu(bn1(z1)) @ W2 + b2 -> back into aggO's buffer, fused col stats
        unsigned* z2 = aggO;
        k_zero_i32<<<NSLOT, 256, 0, stream>>>((int*)stats, NSLOT * 256);
        k_gemm<<<ngemm, 256, 0, stream>>>(
            (const ushort*)z1, Wt2 + (size_t)l * D * D, b2 + l * D,
            scale1, shift1, (ushort*)z2, stats, N_NODES);
        k_bnparams<<<1, D, 0, stream>>>(stats, g2 + l * D, be2 + l * D, scale2, shift2, inv_n);
        // mid layers: BN2+ReLU fused into next agg. last layer: materialize fp32 out.
        if (l == NLAYER - 1)
            k_final<<<(N_NODES * D / 4 + 255) / 256, 256, 0, stream>>>(
                z2, scale2, shift2, (float*)d_out, N_NODES * D / 4);
    }
}

// Round 5
// 995.544 us; speedup vs baseline: 4.3639x; 4.3639x over previous
//
#include <hip/hip_runtime.h>

#define N_NODES 100000
#define N_EDGES 1600000
#define D 128
#define NLAYER 3
#define NSLOT 8
#define NB 1563            // ceil(100000/64) buckets of 64 nodes

typedef __bf16 bf16x8 __attribute__((ext_vector_type(8)));
typedef float f32x4 __attribute__((ext_vector_type(4)));

__device__ inline ushort f2b(float f) {
    union { float f; unsigned u; } v; v.f = f;
    unsigned u = v.u;
    return (ushort)((u + 0x7FFFu + ((u >> 16) & 1u)) >> 16);  // RNE
}
__device__ inline float b2f_lo(unsigned u) {
    union { unsigned u; float f; } v; v.u = u << 16; return v.f;
}
__device__ inline float b2f_hi(unsigned u) {
    union { unsigned u; float f; } v; v.u = u & 0xFFFF0000u; return v.f;
}

// ---------------------------------------------------------------- utility
__global__ void k_zero_i32(int* __restrict__ p, int n) {
    int i = blockIdx.x * blockDim.x + threadIdx.x;
    if (i < n) p[i] = 0;
}

// ---------------------------------------------------------------- bucket build
// LDS-privatized histogram over 1563 buckets (bucket = dst >> 6)
__global__ __launch_bounds__(256)
void k_hist_b(const int* __restrict__ dst, int* __restrict__ bcnt, int e) {
    __shared__ int hs[NB];
    int tid = threadIdx.x;
    for (int i = tid; i < NB; i += 256) hs[i] = 0;
    __syncthreads();
    for (int i = blockIdx.x * 256 + tid; i < e; i += gridDim.x * 256)
        atomicAdd(&hs[dst[i] >> 6], 1);
    __syncthreads();
    for (int i = tid; i < NB; i += 256) {
        int v = hs[i];
        if (v) atomicAdd(&bcnt[i], v);
    }
}

// single-block exclusive scan of NB counts -> boff (+cursor init), boff[NB]=total
__global__ __launch_bounds__(256)
void k_scan_b(const int* __restrict__ bcnt, int* __restrict__ boff,
              int* __restrict__ cur, int total) {
    __shared__ int ts[256];
    int tid = threadIdx.x;
    const int C = (NB + 255) / 256;   // 7
    int s = 0;
    for (int j = 0; j < C; ++j) {
        int i = tid * C + j;
        if (i < NB) s += bcnt[i];
    }
    ts[tid] = s;
    __syncthreads();
    for (int o = 1; o < 256; o <<= 1) {
        int t = (tid >= o) ? ts[tid - o] : 0;
        __syncthreads();
        ts[tid] += t;
        __syncthreads();
    }
    int run = ts[tid] - s;  // exclusive
    for (int j = 0; j < C; ++j) {
        int i = tid * C + j;
        if (i < NB) {
            boff[i] = run; cur[i] = run;
            run += bcnt[i];
        }
    }
    if (tid == 0) boff[NB] = total;
}

// scatter packed edges into bucket-contiguous regions: pack = src*64 | (dst&63)
__global__ __launch_bounds__(256)
void k_bucket(const int* __restrict__ src, const int* __restrict__ dst,
              int* __restrict__ cur, unsigned* __restrict__ bdata, int e) {
    int i = blockIdx.x * 256 + threadIdx.x;
    if (i < e) {
        int d = dst[i];
        int b = d >> 6;
        int p = atomicAdd(&cur[b], 1);
        bdata[p] = ((unsigned)src[i] << 6) | (unsigned)(d & 63);
    }
}

// within-bucket counting sort -> per-node CSR (csrc/offs/deg) with sequential writes
__global__ __launch_bounds__(256)
void k_sortb(const unsigned* __restrict__ bdata, const int* __restrict__ boff,
             int* __restrict__ csrc, int* __restrict__ offs, int* __restrict__ deg, int n) {
    __shared__ int cnt[64], lofs[64], cur[64];
    int b = blockIdx.x, tid = threadIdx.x;
    int e0 = boff[b], ecnt = boff[b + 1] - e0;
    if (tid < 64) cnt[tid] = 0;
    __syncthreads();
    for (int i = tid; i < ecnt; i += 256) atomicAdd(&cnt[bdata[e0 + i] & 63], 1);
    __syncthreads();
    if (tid < 64) {   // one wave: inclusive scan over 64 counts
        int v = cnt[tid];
        int x = v;
        for (int o = 1; o < 64; o <<= 1) {
            int t = __shfl_up(x, o);
            if (tid >= o) x += t;
        }
        lofs[tid] = x - v;
        cur[tid]  = 0;
        int node = b * 64 + tid;
        if (node < n) { offs[node] = e0 + x - v; deg[node] = v; }
    }
    __syncthreads();
    for (int i = tid; i < ecnt; i += 256) {
        unsigned p = bdata[e0 + i];
        int ld = p & 63;
        int pos = atomicAdd(&cur[ld], 1);
        csrc[e0 + lofs[ld] + pos] = (int)(p >> 6);
    }
}

// ---------------------------------------------------------------- aggregation
// Wave per node, register accumulate, 4x-unrolled independent gathers.
// L0: h = x (fp32), out = bf16(x + sum h_j)
__global__ __launch_bounds__(256)
void k_agg_f32(const float* __restrict__ h, const int* __restrict__ offs,
               const int* __restrict__ deg, const int* __restrict__ csrc,
               unsigned* __restrict__ out, int n) {
    int node = blockIdx.x * 4 + (threadIdx.x >> 6);
    if (node >= n) return;
    int lane = threadIdx.x & 63;
    const float2* hp = (const float2*)h;
    float2 acc = hp[node * 64 + lane];
    int s = offs[node], d = deg[node];
    for (int c = 0; c < d; c += 64) {
        int m = min(64, d - c);
        int myi = (lane < m) ? csrc[s + c + lane] : 0;
        int j = 0;
        for (; j + 4 <= m; j += 4) {
            int n0 = __shfl(myi, j + 0), n1 = __shfl(myi, j + 1);
            int n2 = __shfl(myi, j + 2), n3 = __shfl(myi, j + 3);
            float2 v0 = hp[n0 * 64 + lane];
            float2 v1 = hp[n1 * 64 + lane];
            float2 v2 = hp[n2 * 64 + lane];
            float2 v3 = hp[n3 * 64 + lane];
            acc.x += v0.x + v1.x + v2.x + v3.x;
            acc.y += v0.y + v1.y + v2.y + v3.y;
        }
        for (; j < m; ++j) {
            int nb = __shfl(myi, j);
            float2 v = hp[nb * 64 + lane];
            acc.x += v.x; acc.y += v.y;
        }
    }
    out[node * 64 + lane] = (unsigned)f2b(acc.x) | ((unsigned)f2b(acc.y) << 16);
}

// L1,2: h = raw z2 (bf16); fused prev-layer BN2+ReLU: e = relu(z*sc + sh),
// applied to gathered neighbors AND self, accumulated fp32.
__global__ __launch_bounds__(256)
void k_agg_b16(const unsigned* __restrict__ h, const int* __restrict__ offs,
               const int* __restrict__ deg, const int* __restrict__ csrc,
               const float* __restrict__ sc, const float* __restrict__ sh,
               unsigned* __restrict__ out, int n) {
    int node = blockIdx.x * 4 + (threadIdx.x >> 6);
    if (node >= n) return;
    int lane = threadIdx.x & 63;
    float s0 = sc[2 * lane], s1 = sc[2 * lane + 1];
    float t0 = sh[2 * lane], t1 = sh[2 * lane + 1];
    unsigned u = h[node * 64 + lane];
    float ax = b2f_lo(u) * s0 + t0;
    float ay = b2f_hi(u) * s1 + t1;
    ax = ax > 0.f ? ax : 0.f;
    ay = ay > 0.f ? ay : 0.f;
    int s = offs[node], d = deg[node];
    for (int c = 0; c < d; c += 64) {
        int m = min(64, d - c);
        int myi = (lane < m) ? csrc[s + c + lane] : 0;
        int j = 0;
        for (; j + 4 <= m; j += 4) {
            int n0 = __shfl(myi, j + 0), n1 = __shfl(myi, j + 1);
            int n2 = __shfl(myi, j + 2), n3 = __shfl(myi, j + 3);
            unsigned u0 = h[n0 * 64 + lane];
            unsigned u1 = h[n1 * 64 + lane];
            unsigned u2 = h[n2 * 64 + lane];
            unsigned u3 = h[n3 * 64 + lane];
            float x0 = b2f_lo(u0) * s0 + t0, y0 = b2f_hi(u0) * s1 + t1;
            float x1 = b2f_lo(u1) * s0 + t0, y1 = b2f_hi(u1) * s1 + t1;
            float x2 = b2f_lo(u2) * s0 + t0, y2 = b2f_hi(u2) * s1 + t1;
            float x3 = b2f_lo(u3) * s0 + t0, y3 = b2f_hi(u3) * s1 + t1;
            x0 = x0 > 0.f ? x0 : 0.f; y0 = y0 > 0.f ? y0 : 0.f;
            x1 = x1 > 0.f ? x1 : 0.f; y1 = y1 > 0.f ? y1 : 0.f;
            x2 = x2 > 0.f ? x2 : 0.f; y2 = y2 > 0.f ? y2 : 0.f;
            x3 = x3 > 0.f ? x3 : 0.f; y3 = y3 > 0.f ? y3 : 0.f;
            ax += x0 + x1 + x2 + x3;
            ay += y0 + y1 + y2 + y3;
        }
        for (; j < m; ++j) {
            int nb = __shfl(myi, j);
            unsigned uu = h[nb * 64 + lane];
            float xx = b2f_lo(uu) * s0 + t0, yy = b2f_hi(uu) * s1 + t1;
            ax += xx > 0.f ? xx : 0.f;
            ay += yy > 0.f ? yy : 0.f;
        }
    }
    out[node * 64 + lane] = (unsigned)f2b(ax) | ((unsigned)f2b(ay) << 16);
}

// ---------------------------------------------------------------- weight prep
__global__ void k_wprep(const float* __restrict__ W, ushort* __restrict__ Wt) {
    int m = blockIdx.y, nn = blockIdx.x, k = threadIdx.x;
    float v = W[(m * D + k) * D + nn];
    Wt[(m * D + nn) * D + k] = f2b(v);
}

// ---------------------------------------------------------------- MFMA GEMM + fused BN stats
__device__ inline bf16x8 load_frag(const ushort* __restrict__ A, int row, int kb, int n,
                                   const float* __restrict__ ps, const float* __restrict__ psh) {
    bf16x8 r;
    if (row >= n) {
        #pragma unroll
        for (int j = 0; j < 8; ++j) r[j] = (__bf16)0.0f;
        return r;
    }
    if (!ps) return *(const bf16x8*)&A[(size_t)row * D + kb];
    unsigned u[4];
    *(uint4*)u = *(const uint4*)&A[(size_t)row * D + kb];
    #pragma unroll
    for (int p = 0; p < 4; ++p) {
        float lo = b2f_lo(u[p]) * ps[kb + 2 * p] + psh[kb + 2 * p];
        float hi = b2f_hi(u[p]) * ps[kb + 2 * p + 1] + psh[kb + 2 * p + 1];
        lo = lo > 0.f ? lo : 0.f;
        hi = hi > 0.f ? hi : 0.f;
        r[2 * p] = (__bf16)lo;
        r[2 * p + 1] = (__bf16)hi;
    }
    return r;
}

__global__ __launch_bounds__(256)
void k_gemm(const ushort* __restrict__ A, const ushort* __restrict__ Wt,
            const float* __restrict__ bias,
            const float* __restrict__ pre_scale, const float* __restrict__ pre_shift,
            ushort* __restrict__ C, float* __restrict__ stats, int n) {
    __shared__ ushort WtS[128 * 136];  // row stride 272 B (17x16B)

    const uint4* wsrc = (const uint4*)Wt;
    #pragma unroll
    for (int j = 0; j < 8; ++j) {
        int i = threadIdx.x + j * 256;   // 0..2047: row = i>>4, seg = i&15
        int r = i >> 4, s16 = i & 15;
        *(uint4*)&WtS[r * 136 + s16 * 8] = wsrc[i];
    }

    int wv   = threadIdx.x >> 6;
    int lane = threadIdx.x & 63;
    int m16  = lane & 15;
    int kq   = lane >> 4;
    int rowbase = blockIdx.x * 128 + wv * 32;

    bf16x8 a0[4], a1[4];
    #pragma unroll
    for (int ks = 0; ks < 4; ++ks) {
        int kb = ks * 32 + kq * 8;
        a0[ks] = load_frag(A, rowbase + m16, kb, n, pre_scale, pre_shift);
        a1[ks] = load_frag(A, rowbase + 16 + m16, kb, n, pre_scale, pre_shift);
    }

    f32x4 acc0[8], acc1[8];
    #pragma unroll
    for (int t = 0; t < 8; ++t) {
        acc0[t] = (f32x4){0.f, 0.f, 0.f, 0.f};
        acc1[t] = (f32x4){0.f, 0.f, 0.f, 0.f};
    }
    __syncthreads();

    #pragma unroll
    for (int ks = 0; ks < 4; ++ks) {
        #pragma unroll
        for (int t = 0; t < 8; ++t) {
            bf16x8 bfr = *(const bf16x8*)&WtS[(t * 16 + m16) * 136 + ks * 32 + kq * 8];
            acc0[t] = __builtin_amdgcn_mfma_f32_16x16x32_bf16(a0[ks], bfr, acc0[t], 0, 0, 0);
            acc1[t] = __builtin_amdgcn_mfma_f32_16x16x32_bf16(a1[ks], bfr, acc1[t], 0, 0, 0);
        }
    }

    int slot = blockIdx.x & (NSLOT - 1);
    #pragma unroll
    for (int t = 0; t < 8; ++t) {
        int col = t * 16 + m16;
        float bz = bias[col];
        float s = 0.f, q = 0.f;
        #pragma unroll
        for (int mt = 0; mt < 2; ++mt) {
            f32x4 v4 = mt ? acc1[t] : acc0[t];
            #pragma unroll
            for (int rr = 0; rr < 4; ++rr) {
                int row = rowbase + mt * 16 + kq * 4 + rr;
                if (row < n) {
                    float v = v4[rr] + bz;
                    C[(size_t)row * D + col] = f2b(v);
                    s += v; q += v * v;
                }
            }
        }
        s += __shfl_xor(s, 16); q += __shfl_xor(q, 16);
        s += __shfl_xor(s, 32); q += __shfl_xor(q, 32);
        if (kq == 0) {
            atomicAdd(&stats[slot * 256 + col], s);
            atomicAdd(&stats[slot * 256 + 128 + col], q);
        }
    }
}

// ---------------------------------------------------------------- BN param fold
__global__ void k_bnparams(const float* __restrict__ stats, const float* __restrict__ gamma,
                           const float* __restrict__ beta, float* __restrict__ scale,
                           float* __restrict__ shift, float inv_n) {
    int c = threadIdx.x;  // 128
    float s = 0.f, q = 0.f;
    for (int sl = 0; sl < NSLOT; ++sl) {
        s += stats[sl * 256 + c];
        q += stats[sl * 256 + 128 + c];
    }
    float mu  = s * inv_n;
    float var = q * inv_n - mu * mu;
    var = var < 0.f ? 0.f : var;
    float rs = rsqrtf(var + 1e-5f);
    float sc = gamma[c] * rs;
    scale[c] = sc;
    shift[c] = beta[c] - mu * sc;
}

// ---------------------------------------------------------------- final BN (fp32 out, no relu)
__global__ __launch_bounds__(256)
void k_final(const unsigned* __restrict__ z, const float* __restrict__ scale,
             const float* __restrict__ shift, float* __restrict__ outf, int total2) {
    int i = blockIdx.x * 256 + threadIdx.x;  // uint2 = 4 bf16
    if (i >= total2) return;
    uint2 u = ((const uint2*)z)[i];
    int c = (i * 4) & (D - 1);
    float4 o;
    o.x = b2f_lo(u.x) * scale[c + 0] + shift[c + 0];
    o.y = b2f_hi(u.x) * scale[c + 1] + shift[c + 1];
    o.z = b2f_lo(u.y) * scale[c + 2] + shift[c + 2];
    o.w = b2f_hi(u.y) * scale[c + 3] + shift[c + 3];
    ((float4*)outf)[i] = o;
}

// ---------------------------------------------------------------- launch
extern "C" void kernel_launch(void* const* d_in, const int* in_sizes, int n_in,
                              void* d_out, int out_size, void* d_ws, size_t ws_size,
                              hipStream_t stream) {
    const float* x   = (const float*)d_in[0];
    const int*   ei  = (const int*)d_in[1];
    const float* W1  = (const float*)d_in[4];
    const float* b1  = (const float*)d_in[5];
    const float* g1  = (const float*)d_in[6];
    const float* be1 = (const float*)d_in[7];
    const float* W2  = (const float*)d_in[8];
    const float* b2  = (const float*)d_in[9];
    const float* g2  = (const float*)d_in[10];
    const float* be2 = (const float*)d_in[11];

    const int* srcI = ei;
    const int* dstI = ei + N_EDGES;

    // workspace layout (~70 MB)
    char* ws = (char*)d_ws;
    unsigned* bufA = (unsigned*)ws; ws += (size_t)N_NODES * 64 * 4 + 65536;
    unsigned* bufB = (unsigned*)ws; ws += (size_t)N_NODES * 64 * 4 + 65536;
    unsigned* bdata = (unsigned*)ws; ws += (size_t)N_EDGES * 4;
    int* csrc    = (int*)ws;   ws += (size_t)N_EDGES * 4;
    int* bcnt    = (int*)ws;   ws += (NB + 16) * 4;
    int* boff    = (int*)ws;   ws += (NB + 16) * 4;
    int* cur     = (int*)ws;   ws += (NB + 16) * 4;
    int* offs    = (int*)ws;   ws += (size_t)N_NODES * 4;
    int* deg     = (int*)ws;   ws += (size_t)N_NODES * 4;
    ushort* Wt1  = (ushort*)ws; ws += 3 * D * D * 2;
    ushort* Wt2  = (ushort*)ws; ws += 3 * D * D * 2;
    float* stats = (float*)ws; ws += NSLOT * 256 * 4;
    float* scale1 = (float*)ws; ws += 512;
    float* shift1 = (float*)ws; ws += 512;
    float* scale2 = (float*)ws; ws += 512;
    float* shift2 = (float*)ws; ws += 512;

    // ---- weight prep ----
    k_wprep<<<dim3(D, 3), D, 0, stream>>>(W1, Wt1);
    k_wprep<<<dim3(D, 3), D, 0, stream>>>(W2, Wt2);

    // ---- bucket build + within-bucket sort -> per-node CSR ----
    k_zero_i32<<<(NB + 255) / 256, 256, 0, stream>>>(bcnt, NB);
    k_hist_b<<<256, 256, 0, stream>>>(dstI, bcnt, N_EDGES);
    k_scan_b<<<1, 256, 0, stream>>>(bcnt, boff, cur, N_EDGES);
    k_bucket<<<(N_EDGES + 255) / 256, 256, 0, stream>>>(srcI, dstI, cur, bdata, N_EDGES);
    k_sortb<<<NB, 256, 0, stream>>>(bdata, boff, csrc, offs, deg, N_NODES);

    const float inv_n = 1.0f / (float)N_NODES;
    int ngemm = (N_NODES + 127) / 128;  // 782
    int nagg  = (N_NODES + 3) / 4;

    for (int l = 0; l < NLAYER; ++l) {
        // agg (+ fused prev BN2/ReLU for l>0)
        unsigned* aggO = (l & 1) ? bufB : bufA;          // l=0:A, l=1:B, l=2:A
        if (l == 0)
            k_agg_f32<<<nagg, 256, 0, stream>>>(x, offs, deg, csrc, aggO, N_NODES);
        else {
            const unsigned* hz = (l & 1) ? bufA : bufB;  // previous raw z2
            k_agg_b16<<<nagg, 256, 0, stream>>>(hz, offs, deg, csrc, scale2, shift2, aggO, N_NODES);
        }
        // z1 = aggO @ W1 + b1 -> other buffer, fused col stats
        unsigned* z1 = (aggO == bufA) ? bufB : bufA;
        k_zero_i32<<<NSLOT, 256, 0, stream>>>((int*)stats, NSLOT * 256);
        k_gemm<<<ngemm, 256, 0, stream>>>(
            (const ushort*)aggO, Wt1 + (size_t)l * D * D, b1 + l * D,
            nullptr, nullptr, (ushort*)z1, stats, N_NODES);
        k_bnparams<<<1, D, 0, stream>>>(stats, g1 + l * D, be1 + l * D, scale1, shift1, inv_n);
        // z2 = relu(bn1(z1)) @ W2 + b2 -> back into aggO buffer (raw), fused col stats
        unsigned* z2 = aggO;
        k_zero_i32<<<NSLOT, 256, 0, stream>>>((int*)stats, NSLOT * 256);
        k_gemm<<<ngemm, 256, 0, stream>>>(
            (const ushort*)z1, Wt2 + (size_t)l * D * D, b2 + l * D,
            scale1, shift1, (ushort*)z2, stats, N_NODES);
        k_bnparams<<<1, D, 0, stream>>>(stats, g2 + l * D, be2 + l * D, scale2, shift2, inv_n);
        // last layer: materialize fp32 out
        if (l == NLAYER - 1)
            k_final<<<(N_NODES * D / 4 + 255) / 256, 256, 0, stream>>>(
                z2, scale2, shift2, (float*)d_out, N_NODES * D / 4);
    }
}